// Round 5
// baseline (5785.062 us; speedup 1.0000x reference)
//
#include <hip/hip_runtime.h>
#include <hip/hip_bf16.h>

#define NP 500000
#define NM 10000
#define EPS 1e-5f
#define TM 32

// ws layout (bytes)
#define WS_OFFS  0            // (NM+1) ints
#define WS_PART1 65536        // 64*512 f32  (bucketed BN1 partial sum/sumsq)
#define WS_PART2 196608       // 64*256 f32  (bucketed BN2 partial)
#define WS_BN1   262144       // a1[256], c1[256]
#define WS_BN2   264192       // a2[128], c2[128]
#define WS_HPAIR 524288       // NM*128 f32
#define WS_Y1    6291456      // NM*128 f32
#define WS_Z     16777216     // NP*256 (f32 or bf16)

template<typename ZT> __device__ inline ZT to_z(float v);
template<> __device__ inline float to_z<float>(float v) { return v; }
template<> __device__ inline __hip_bfloat16 to_z<__hip_bfloat16>(float v) { return __float2bfloat16(v); }
template<typename ZT> __device__ inline float from_z(ZT v);
template<> __device__ inline float from_z<float>(float v) { return v; }
template<> __device__ inline float from_z<__hip_bfloat16>(__hip_bfloat16 v) { return __bfloat162float(v); }

// ---- prep: zero stat partials + exclusive-scan segment lengths -> offsets
__global__ void kprep(const int* __restrict__ len, int* __restrict__ offs,
                      float* __restrict__ part1, float* __restrict__ part2) {
    int tid = threadIdx.x;  // 256
    for (int i = tid; i < 64 * 512; i += 256) part1[i] = 0.f;
    for (int i = tid; i < 64 * 256; i += 256) part2[i] = 0.f;
    const int CH = (NM + 255) / 256;  // 40
    int c0 = tid * CH;
    int s = 0;
    for (int i = 0; i < CH; ++i) { int g = c0 + i; if (g < NM) s += len[g]; }
    __shared__ int ps[256];
    ps[tid] = s;
    __syncthreads();
    for (int d = 1; d < 256; d <<= 1) {
        int v = (tid >= d) ? ps[tid - d] : 0;
        __syncthreads();
        ps[tid] += v;
        __syncthreads();
    }
    int run = (tid == 0) ? 0 : ps[tid - 1];
    if (tid == 0) offs[0] = 0;
    for (int i = 0; i < CH; ++i) {
        int g = c0 + i;
        if (g < NM) { run += len[g]; offs[g + 1] = run; }
    }
}

// ---- K1: fused embed (atom1|atom2|bond, relu) + p1 GEMM (+bias), write z, BN1 stats
// 32 rows/block, 256 threads, thread = 2 rows x 16 cols. h in LDS (stride 321: conflict-free).
template<typename ZT>
__launch_bounds__(256, 3)
__global__ void k1(const float* __restrict__ xp, const float* __restrict__ atom_W,
                   const float* __restrict__ atom_b, const float* __restrict__ bond_W,
                   const float* __restrict__ bond_b, const float* __restrict__ p1_W,
                   const float* __restrict__ p1_b, ZT* __restrict__ z,
                   float* __restrict__ part1) {
    __shared__ float h_lds[TM][321];
    __shared__ float x_lds[TM][80];
    __shared__ float sstat[512];
    int tid = threadIdx.x;
    long r0 = (long)blockIdx.x * TM;

    for (int i = tid; i < 512; i += 256) sstat[i] = 0.f;
    for (int i = tid; i < TM * 80; i += 256) {
        int r = i / 80, c = i % 80;
        long gr = r0 + r;
        x_lds[r][c] = (gr < NP) ? xp[gr * 80 + c] : 0.f;
    }
    __syncthreads();

    // phase 1: h tile (weights via L1 — tiny share of FLOPs)
    for (int e = tid; e < TM * 320; e += 256) {
        int r = e / 320, c = e % 320;
        float acc;
        if (c < 128) {
            acc = atom_b[c];
            #pragma unroll
            for (int i = 0; i < 32; ++i) acc = fmaf(x_lds[r][i], atom_W[i * 128 + c], acc);
        } else if (c < 256) {
            int cc = c - 128;
            acc = atom_b[cc];
            #pragma unroll
            for (int i = 0; i < 32; ++i) acc = fmaf(x_lds[r][32 + i], atom_W[i * 128 + cc], acc);
        } else {
            int cc = c - 256;
            acc = bond_b[cc];
            #pragma unroll
            for (int i = 0; i < 16; ++i) acc = fmaf(x_lds[r][64 + i], bond_W[i * 64 + cc], acc);
        }
        h_lds[r][c] = fmaxf(acc, 0.f);
    }
    __syncthreads();

    // phase 2: z[2 rows][16 cols] per thread, K=320
    int cg = tid & 15;   // col group: cols cg*16..+15
    int rg = tid >> 4;   // row group: rows rg*2, rg*2+1
    float a0[16], a1[16];
    #pragma unroll
    for (int j = 0; j < 16; ++j) { a0[j] = 0.f; a1[j] = 0.f; }
    const float* Wb = p1_W + cg * 16;
    #pragma unroll 2
    for (int k = 0; k < 320; ++k) {
        const float* wr = Wb + k * 256;
        float w[16];
        *(float4*)(w + 0)  = *(const float4*)(wr + 0);
        *(float4*)(w + 4)  = *(const float4*)(wr + 4);
        *(float4*)(w + 8)  = *(const float4*)(wr + 8);
        *(float4*)(w + 12) = *(const float4*)(wr + 12);
        float h0 = h_lds[rg * 2][k];
        float h1 = h_lds[rg * 2 + 1][k];
        #pragma unroll
        for (int j = 0; j < 16; ++j) {
            a0[j] = fmaf(h0, w[j], a0[j]);
            a1[j] = fmaf(h1, w[j], a1[j]);
        }
    }

    float bb[16];
    #pragma unroll
    for (int j = 0; j < 16; ++j) bb[j] = p1_b[cg * 16 + j];

    float sc[16], qc[16];
    #pragma unroll
    for (int j = 0; j < 16; ++j) { sc[j] = 0.f; qc[j] = 0.f; }
    #pragma unroll
    for (int a = 0; a < 2; ++a) {
        long r = r0 + rg * 2 + a;
        if (r < NP) {
            long base = r * 256 + cg * 16;
            #pragma unroll
            for (int j = 0; j < 16; ++j) {
                float v = (a == 0 ? a0[j] : a1[j]) + bb[j];
                ZT q = to_z<ZT>(v);
                z[base + j] = q;
                float vq = from_z<ZT>(q);   // stats on what K3 will read
                sc[j] += vq;
                qc[j] += vq * vq;
            }
        }
    }
    #pragma unroll
    for (int j = 0; j < 16; ++j) {
        atomicAdd(&sstat[cg * 16 + j], sc[j]);
        atomicAdd(&sstat[256 + cg * 16 + j], qc[j]);
    }
    __syncthreads();
    int bucket = blockIdx.x & 63;
    for (int i = tid; i < 512; i += 256) atomicAdd(&part1[bucket * 512 + i], sstat[i]);
}

// ---- K2: finalize BN1 -> a1[f] = rs*g, c1[f] = beta - mu*rs*g
__global__ void k2(const float* __restrict__ part1, const float* __restrict__ g,
                   const float* __restrict__ beta, float* __restrict__ bn1) {
    int f = threadIdx.x;  // 256
    float s = 0.f, q = 0.f;
    for (int b = 0; b < 64; ++b) { s += part1[b * 512 + f]; q += part1[b * 512 + 256 + f]; }
    float mu = s / (float)NP;
    float var = fmaxf(q / (float)NP - mu * mu, 0.f);
    float a = rsqrtf(var + EPS) * g[f];
    bn1[f] = a;
    bn1[256 + f] = beta[f] - mu * a;
}

// ---- K3: per molecule: T[k] = mean_rows relu(z*a1+c1); h_pair = T @ p3_W + p3_b
template<typename ZT>
__global__ void k3(const ZT* __restrict__ z, const int* __restrict__ offs,
                   const float* __restrict__ bn1, const float* __restrict__ p3_W,
                   const float* __restrict__ p3_b, float* __restrict__ hpair) {
    int mol = blockIdx.x;
    int tid = threadIdx.x;  // 256 = one feature k each
    int s = offs[mol], e = offs[mol + 1];
    float a = bn1[tid], c = bn1[256 + tid];
    float T = 0.f;
    for (int r = s; r < e; ++r)
        T += fmaxf(fmaf(from_z<ZT>(z[(long)r * 256 + tid]), a, c), 0.f);
    __shared__ float Tl[256];
    Tl[tid] = T / (float)(e - s);
    __syncthreads();
    int f = tid & 127, half = tid >> 7;
    float acc = 0.f;
    const float* W = p3_W + half * 128 * 128 + f;
    #pragma unroll 4
    for (int kk = 0; kk < 128; ++kk) acc = fmaf(Tl[half * 128 + kk], W[kk * 128], acc);
    __shared__ float red[256];
    red[tid] = acc;
    __syncthreads();
    if (tid < 128) hpair[(long)mol * 128 + tid] = red[tid] + red[128 + tid] + p3_b[tid];
}

// ---- K4: y1 = h_pair @ fc1_W + b, BN2 stats (16 mols/block)
__global__ void k4(const float* __restrict__ hpair, const float* __restrict__ fc1_W,
                   const float* __restrict__ fc1_b, float* __restrict__ y1,
                   float* __restrict__ part2) {
    __shared__ float hp[16][128];
    __shared__ float st2[256];
    int tid = threadIdx.x;
    int base = blockIdx.x * 16;
    st2[tid] = 0.f;
    for (int i = tid; i < 16 * 128; i += 256)
        hp[i >> 7][i & 127] = hpair[(long)(base + (i >> 7)) * 128 + (i & 127)];
    __syncthreads();
    int f = tid & 127, rh = tid >> 7;
    float s = 0.f, q = 0.f;
    float bias = fc1_b[f];
    for (int rr = 0; rr < 8; ++rr) {
        int row = rh * 8 + rr;
        float acc = bias;
        #pragma unroll 4
        for (int k = 0; k < 128; ++k) acc = fmaf(hp[row][k], fc1_W[k * 128 + f], acc);
        y1[(long)(base + row) * 128 + f] = acc;
        s += acc; q += acc * acc;
    }
    atomicAdd(&st2[f], s);
    atomicAdd(&st2[128 + f], q);
    __syncthreads();
    int bucket = blockIdx.x & 63;
    atomicAdd(&part2[bucket * 256 + tid], st2[tid]);
}

// ---- K5: finalize BN2
__global__ void k5(const float* __restrict__ part2, const float* __restrict__ g,
                   const float* __restrict__ beta, float* __restrict__ bn2) {
    int f = threadIdx.x;  // 128
    float s = 0.f, q = 0.f;
    for (int b = 0; b < 64; ++b) { s += part2[b * 256 + f]; q += part2[b * 256 + 128 + f]; }
    float mu = s / (float)NM;
    float var = fmaxf(q / (float)NM - mu * mu, 0.f);
    float a = rsqrtf(var + EPS) * g[f];
    bn2[f] = a;
    bn2[128 + f] = beta[f] - mu * a;
}

// ---- K6: out = relu(y1*a2+c2) @ fc2_W + fc2_b
__global__ void k6(const float* __restrict__ y1, const float* __restrict__ bn2,
                   const float* __restrict__ fc2_W, const float* __restrict__ fc2_b,
                   float* __restrict__ out) {
    int mol = blockIdx.x * 256 + threadIdx.x;
    if (mol >= NM) return;
    float acc = fc2_b[0];
    const float4* yp = (const float4*)(y1 + (long)mol * 128);
    #pragma unroll 8
    for (int i = 0; i < 32; ++i) {
        float4 y = yp[i];
        float4 a = *(const float4*)(bn2 + i * 4);
        float4 c = *(const float4*)(bn2 + 128 + i * 4);
        float4 w = *(const float4*)(fc2_W + i * 4);
        acc += fmaxf(fmaf(y.x, a.x, c.x), 0.f) * w.x;
        acc += fmaxf(fmaf(y.y, a.y, c.y), 0.f) * w.y;
        acc += fmaxf(fmaf(y.z, a.z, c.z), 0.f) * w.z;
        acc += fmaxf(fmaf(y.w, a.w, c.w), 0.f) * w.w;
    }
    out[mol] = acc;
}

extern "C" void kernel_launch(void* const* d_in, const int* in_sizes, int n_in,
                              void* d_out, int out_size, void* d_ws, size_t ws_size,
                              hipStream_t stream) {
    const float* xp     = (const float*)d_in[0];
    const int*   lens   = (const int*)d_in[1];
    const float* atom_W = (const float*)d_in[2];
    const float* atom_b = (const float*)d_in[3];
    const float* bond_W = (const float*)d_in[4];
    const float* bond_b = (const float*)d_in[5];
    const float* p1_W   = (const float*)d_in[6];
    const float* p1_b   = (const float*)d_in[7];
    const float* p_bn_g = (const float*)d_in[8];
    const float* p_bn_b = (const float*)d_in[9];
    const float* p3_W   = (const float*)d_in[10];
    const float* p3_b   = (const float*)d_in[11];
    const float* fc1_W  = (const float*)d_in[12];
    const float* fc1_b  = (const float*)d_in[13];
    const float* bn1_g  = (const float*)d_in[14];
    const float* bn1_b  = (const float*)d_in[15];
    const float* fc2_W  = (const float*)d_in[16];
    const float* fc2_b  = (const float*)d_in[17];
    float* out = (float*)d_out;
    char* ws = (char*)d_ws;

    int*   offs  = (int*)(ws + WS_OFFS);
    float* part1 = (float*)(ws + WS_PART1);
    float* part2 = (float*)(ws + WS_PART2);
    float* bn1   = (float*)(ws + WS_BN1);
    float* bn2   = (float*)(ws + WS_BN2);
    float* hpair = (float*)(ws + WS_HPAIR);
    float* y1    = (float*)(ws + WS_Y1);

    // z = [NP,256]: f32 if ws allows (529 MB), else bf16 fallback (273 MB)
    bool zf32 = ws_size >= (size_t)WS_Z + (size_t)NP * 256 * 4;

    kprep<<<1, 256, 0, stream>>>(lens, offs, part1, part2);
    if (zf32) {
        float* z = (float*)(ws + WS_Z);
        k1<float><<<(NP + TM - 1) / TM, 256, 0, stream>>>(xp, atom_W, atom_b, bond_W, bond_b, p1_W, p1_b, z, part1);
        k2<<<1, 256, 0, stream>>>(part1, p_bn_g, p_bn_b, bn1);
        k3<float><<<NM, 256, 0, stream>>>(z, offs, bn1, p3_W, p3_b, hpair);
    } else {
        __hip_bfloat16* z = (__hip_bfloat16*)(ws + WS_Z);
        k1<__hip_bfloat16><<<(NP + TM - 1) / TM, 256, 0, stream>>>(xp, atom_W, atom_b, bond_W, bond_b, p1_W, p1_b, z, part1);
        k2<<<1, 256, 0, stream>>>(part1, p_bn_g, p_bn_b, bn1);
        k3<__hip_bfloat16><<<NM, 256, 0, stream>>>(z, offs, bn1, p3_W, p3_b, hpair);
    }
    k4<<<(NM + 15) / 16, 256, 0, stream>>>(hpair, fc1_W, fc1_b, y1, part2);
    k5<<<1, 128, 0, stream>>>(part2, bn1_g, bn1_b, bn2);
    k6<<<(NM + 255) / 256, 256, 0, stream>>>(y1, bn2, fc2_W, fc2_b, out);
}

// Round 10
// 1069.858 us; speedup vs baseline: 5.4073x; 5.4073x over previous
//
#include <hip/hip_runtime.h>

#define NP 500000
#define NM 10000
#define EPS 1e-5f
#define VTOL 4e-3f

// ws layout (bytes)
#define WS_OFFS  0            // (NM+1) ints
#define WS_FLAG  40960        // int: 1 = MFMA z good
#define WS_PART1 65536        // 64*512 f32 (bucketed BN1 sum/sumsq)
#define WS_PART2 196608       // 64*256 f32
#define WS_BN1   262144       // a1[256], c1[256]
#define WS_BN2   264192       // a2[128], c2[128]
#define WS_WE    270336       // packed embed W: 20*3*64*8 bf16
#define WS_W1    331776       // packed p1_W: 16*10*64*8 bf16
#define WS_HPAIR 524288       // NM*128 f32
#define WS_Y1    6291456      // NM*128 f32
#define WS_Z     16777216     // NP*256 bf16 = 256 MB

typedef float f32x4 __attribute__((ext_vector_type(4)));
typedef unsigned short u16x8 __attribute__((ext_vector_type(8)));

__device__ inline unsigned short f2b(float f) {
    unsigned int u = __builtin_bit_cast(unsigned int, f);
    unsigned int r = u + 0x7FFFu + ((u >> 16) & 1u);
    return (unsigned short)(r >> 16);
}
__device__ inline float b2f(unsigned short s) {
    return __builtin_bit_cast(float, (unsigned int)s << 16);
}
// D = A(16x32)*B(32x16) + D. A/B pack: idx=lane&15 (A row / B col), k=(lane>>4)*8+j.
// C/D: col=lane&15, row=(lane>>4)*4+reg (HW-verified).
__device__ inline void mfma_bf16(f32x4& d, u16x8 a, u16x8 b) {
    asm volatile("v_mfma_f32_16x16x32_bf16 %0, %1, %2, %0" : "+v"(d) : "v"(a), "v"(b));
}

// ---- prep: zero partials, flag=1, exclusive-scan lengths
__global__ void kprep(const int* __restrict__ len, int* __restrict__ offs,
                      float* __restrict__ part1, float* __restrict__ part2,
                      int* __restrict__ flag) {
    int tid = threadIdx.x;  // 256
    if (tid == 0) *flag = 1;
    for (int i = tid; i < 64 * 512; i += 256) part1[i] = 0.f;
    for (int i = tid; i < 64 * 256; i += 256) part2[i] = 0.f;
    const int CH = (NM + 255) / 256;
    int c0 = tid * CH;
    int s = 0;
    for (int i = 0; i < CH; ++i) { int g = c0 + i; if (g < NM) s += len[g]; }
    __shared__ int ps[256];
    ps[tid] = s;
    __syncthreads();
    for (int d = 1; d < 256; d <<= 1) {
        int v = (tid >= d) ? ps[tid - d] : 0;
        __syncthreads();
        ps[tid] += v;
        __syncthreads();
    }
    int run = (tid == 0) ? 0 : ps[tid - 1];
    if (tid == 0) offs[0] = 0;
    for (int i = 0; i < CH; ++i) {
        int g = c0 + i;
        if (g < NM) { run += len[g]; offs[g + 1] = run; }
    }
}

// ---- pack embed weights: block-diag [96 x 320] -> [n][kk][lane][8]
__global__ void kpack_we(const float* __restrict__ atom_W, const float* __restrict__ bond_W,
                         unsigned short* __restrict__ we) {
    int id = blockIdx.x * 256 + threadIdx.x;  // < 30720
    if (id >= 30720) return;
    int e = id >> 3, j = id & 7;
    int l = e & 63, t = e >> 6;
    int kk = t % 3, n = t / 3;
    int k = kk * 32 + ((l >> 4) << 3) + j;
    int col = n * 16 + (l & 15);
    float v = 0.f;
    if (k < 32)      { if (col < 128) v = atom_W[k * 128 + col]; }
    else if (k < 64) { if (col >= 128 && col < 256) v = atom_W[(k - 32) * 128 + (col - 128)]; }
    else if (k < 80) { if (col >= 256) v = bond_W[(k - 64) * 64 + (col - 256)]; }
    we[id] = f2b(v);
}

// ---- pack p1_W [320 x 256] -> [n][kk][lane][8]
__global__ void kpack_w1(const float* __restrict__ p1_W, unsigned short* __restrict__ w1) {
    int id = blockIdx.x * 256 + threadIdx.x;  // < 81920
    if (id >= 81920) return;
    int e = id >> 3, j = id & 7;
    int l = e & 63, t = e >> 6;
    int kk = t % 10, n = t / 10;
    int k = kk * 32 + ((l >> 4) << 3) + j;
    int col = n * 16 + (l & 15);
    w1[id] = f2b(p1_W[k * 256 + col]);
}

// ---- K1M: MFMA embed + p1, writes z (bf16). 64 rows/block, 4 waves.
__launch_bounds__(256, 2)
__global__ void k1m(const float* __restrict__ xp,
                    const float* __restrict__ atom_b, const float* __restrict__ bond_b,
                    const unsigned short* __restrict__ wep,
                    const unsigned short* __restrict__ w1p,
                    const float* __restrict__ p1_b,
                    unsigned short* __restrict__ z) {
    __shared__ __align__(16) unsigned short x_frag[4 * 3 * 64 * 8];   // 12288 B
    __shared__ __align__(16) unsigned short h_frag[4 * 10 * 64 * 8];  // 40960 B (reused for z-transpose)
    int tid = threadIdx.x;
    int l = tid & 63, w = tid >> 6;
    long r0 = (long)blockIdx.x * 64;

    // stage x: x[r][c] (c<80, pad to 96) -> fragment layout [m][kk][lane][j]
    for (int id = tid; id < 64 * 96; id += 256) {
        int r = id / 96, c = id - r * 96;
        float v = 0.f;
        long gr = r0 + r;
        if (c < 80 && gr < NP) v = xp[gr * 80 + c];
        int lane = (r & 15) | (((c & 31) >> 3) << 4);
        int idx = ((((r >> 4) * 3 + (c >> 5)) * 64 + lane) << 3) | (c & 7);
        x_frag[idx] = f2b(v);
    }
    __syncthreads();

    int rr = (l >> 4) << 2;  // C/D row base
    int cb = l & 15;         // C/D col

    // ---- embed: h[64][320] = x[64][96] @ We[96][320], +bias, relu
    {
        f32x4 acc[5][4];
        #pragma unroll
        for (int ni = 0; ni < 5; ++ni)
            #pragma unroll
            for (int m = 0; m < 4; ++m) acc[ni][m] = (f32x4)0.f;
        #pragma unroll
        for (int kk = 0; kk < 3; ++kk) {
            u16x8 a[4];
            #pragma unroll
            for (int m = 0; m < 4; ++m)
                a[m] = *(const u16x8*)&x_frag[((m * 3 + kk) * 64 + l) << 3];
            #pragma unroll
            for (int ni = 0; ni < 5; ++ni) {
                u16x8 b = *(const u16x8*)&wep[(((w * 5 + ni) * 3 + kk) * 64 + l) << 3];
                #pragma unroll
                for (int m = 0; m < 4; ++m) mfma_bf16(acc[ni][m], a[m], b);
            }
        }
        __builtin_amdgcn_sched_barrier(0);
        #pragma unroll
        for (int ni = 0; ni < 5; ++ni) {
            int col = (w * 5 + ni) * 16 + cb;
            float bias = (col < 256) ? atom_b[col & 127] : bond_b[col - 256];
            int kkh = col >> 5;
            int lanehi = ((col & 31) >> 3) << 4;
            int jh = col & 7;
            #pragma unroll
            for (int m = 0; m < 4; ++m)
                #pragma unroll
                for (int q = 0; q < 4; ++q) {
                    float v = fmaxf(acc[ni][m][q] + bias, 0.f);
                    h_frag[(((m * 10 + kkh) * 64 + ((rr + q) | lanehi)) << 3) | jh] = f2b(v);
                }
        }
    }
    __syncthreads();

    // ---- p1: z[64][256] = h[64][320] @ W1[320][256] + bias
    f32x4 accz[4][4];
    #pragma unroll
    for (int ni = 0; ni < 4; ++ni)
        #pragma unroll
        for (int m = 0; m < 4; ++m) accz[ni][m] = (f32x4)0.f;
    #pragma unroll 2
    for (int kk = 0; kk < 10; ++kk) {
        u16x8 a[4];
        #pragma unroll
        for (int m = 0; m < 4; ++m)
            a[m] = *(const u16x8*)&h_frag[((m * 10 + kk) * 64 + l) << 3];
        #pragma unroll
        for (int ni = 0; ni < 4; ++ni) {
            u16x8 b = *(const u16x8*)&w1p[(((w * 4 + ni) * 10 + kk) * 64 + l) << 3];
            #pragma unroll
            for (int m = 0; m < 4; ++m) mfma_bf16(accz[ni][m], a[m], b);
        }
    }
    __builtin_amdgcn_sched_barrier(0);
    float bias1[4];
    #pragma unroll
    for (int ni = 0; ni < 4; ++ni) bias1[ni] = p1_b[(w * 4 + ni) * 16 + cb];
    __syncthreads();  // all h_frag reads done -> safe to overlay z-transpose

    unsigned short* ztw = h_frag + w * 4608;  // 64 rows x 72 ushorts, wave-private
    #pragma unroll
    for (int ni = 0; ni < 4; ++ni)
        #pragma unroll
        for (int m = 0; m < 4; ++m)
            #pragma unroll
            for (int q = 0; q < 4; ++q)
                ztw[(m * 16 + rr + q) * 72 + ni * 16 + cb] = f2b(accz[ni][m][q] + bias1[ni]);
    #pragma unroll
    for (int i = 0; i < 8; ++i) {
        int chunk = i * 64 + l;
        int row = chunk >> 3, cc = chunk & 7;
        long gr = r0 + row;
        if (gr < NP)
            *(u16x8*)&z[gr * 256 + w * 64 + cc * 8] = *(const u16x8*)&ztw[row * 72 + cc * 8];
    }
}

// ---- verify: f32 recompute of 512 scattered rows vs z; clear flag on mismatch
__global__ void kverify(const float* __restrict__ xp, const float* __restrict__ atom_W,
                        const float* __restrict__ atom_b, const float* __restrict__ bond_W,
                        const float* __restrict__ bond_b, const float* __restrict__ p1_W,
                        const float* __restrict__ p1_b, const unsigned short* __restrict__ z,
                        int* __restrict__ flag) {
    __shared__ float h_lds[32][321];
    __shared__ float x_lds[32][80];
    int tid = threadIdx.x;
    long r0 = (long)blockIdx.x * 33331;
    if (r0 > NP - 32) r0 = NP - 32;
    for (int i = tid; i < 32 * 80; i += 256) {
        int r = i / 80, c = i % 80;
        x_lds[r][c] = xp[(r0 + r) * 80 + c];
    }
    __syncthreads();
    for (int e = tid; e < 32 * 320; e += 256) {
        int r = e / 320, c = e % 320;
        float acc;
        if (c < 128) {
            acc = atom_b[c];
            #pragma unroll
            for (int i = 0; i < 32; ++i) acc = fmaf(x_lds[r][i], atom_W[i * 128 + c], acc);
        } else if (c < 256) {
            int cc = c - 128;
            acc = atom_b[cc];
            #pragma unroll
            for (int i = 0; i < 32; ++i) acc = fmaf(x_lds[r][32 + i], atom_W[i * 128 + cc], acc);
        } else {
            int cc = c - 256;
            acc = bond_b[cc];
            #pragma unroll
            for (int i = 0; i < 16; ++i) acc = fmaf(x_lds[r][64 + i], bond_W[i * 64 + cc], acc);
        }
        h_lds[r][c] = fmaxf(acc, 0.f);
    }
    __syncthreads();
    int cg = tid & 15, rg = tid >> 4;
    float a0[16], a1[16];
    #pragma unroll
    for (int j = 0; j < 16; ++j) { a0[j] = 0.f; a1[j] = 0.f; }
    const float* Wb = p1_W + cg * 16;
    for (int k = 0; k < 320; ++k) {
        const float* wr = Wb + k * 256;
        float wv[16];
        *(float4*)(wv + 0)  = *(const float4*)(wr + 0);
        *(float4*)(wv + 4)  = *(const float4*)(wr + 4);
        *(float4*)(wv + 8)  = *(const float4*)(wr + 8);
        *(float4*)(wv + 12) = *(const float4*)(wr + 12);
        float h0 = h_lds[rg * 2][k];
        float h1 = h_lds[rg * 2 + 1][k];
        #pragma unroll
        for (int j = 0; j < 16; ++j) {
            a0[j] = fmaf(h0, wv[j], a0[j]);
            a1[j] = fmaf(h1, wv[j], a1[j]);
        }
    }
    bool bad = false;
    #pragma unroll
    for (int a = 0; a < 2; ++a) {
        long r = r0 + rg * 2 + a;
        #pragma unroll
        for (int j = 0; j < 16; ++j) {
            float v = (a == 0 ? a0[j] : a1[j]) + p1_b[cg * 16 + j];
            float got = b2f(z[r * 256 + cg * 16 + j]);
            if (fabsf(got - v) > VTOL) bad = true;
        }
    }
    if (bad) *flag = 0;
}

// ---- fallback f32 k1 (certified): runs only if flag==0; writes z bf16
__launch_bounds__(256, 3)
__global__ void k1f(const int* __restrict__ flag, const float* __restrict__ xp,
                    const float* __restrict__ atom_W, const float* __restrict__ atom_b,
                    const float* __restrict__ bond_W, const float* __restrict__ bond_b,
                    const float* __restrict__ p1_W, const float* __restrict__ p1_b,
                    unsigned short* __restrict__ z) {
    if (*flag) return;
    __shared__ float h_lds[32][321];
    __shared__ float x_lds[32][80];
    int tid = threadIdx.x;
    long r0 = (long)blockIdx.x * 32;
    for (int i = tid; i < 32 * 80; i += 256) {
        int r = i / 80, c = i % 80;
        long gr = r0 + r;
        x_lds[r][c] = (gr < NP) ? xp[gr * 80 + c] : 0.f;
    }
    __syncthreads();
    for (int e = tid; e < 32 * 320; e += 256) {
        int r = e / 320, c = e % 320;
        float acc;
        if (c < 128) {
            acc = atom_b[c];
            #pragma unroll
            for (int i = 0; i < 32; ++i) acc = fmaf(x_lds[r][i], atom_W[i * 128 + c], acc);
        } else if (c < 256) {
            int cc = c - 128;
            acc = atom_b[cc];
            #pragma unroll
            for (int i = 0; i < 32; ++i) acc = fmaf(x_lds[r][32 + i], atom_W[i * 128 + cc], acc);
        } else {
            int cc = c - 256;
            acc = bond_b[cc];
            #pragma unroll
            for (int i = 0; i < 16; ++i) acc = fmaf(x_lds[r][64 + i], bond_W[i * 64 + cc], acc);
        }
        h_lds[r][c] = fmaxf(acc, 0.f);
    }
    __syncthreads();
    int cg = tid & 15, rg = tid >> 4;
    float a0[16], a1[16];
    #pragma unroll
    for (int j = 0; j < 16; ++j) { a0[j] = 0.f; a1[j] = 0.f; }
    const float* Wb = p1_W + cg * 16;
    #pragma unroll 2
    for (int k = 0; k < 320; ++k) {
        const float* wr = Wb + k * 256;
        float wv[16];
        *(float4*)(wv + 0)  = *(const float4*)(wr + 0);
        *(float4*)(wv + 4)  = *(const float4*)(wr + 4);
        *(float4*)(wv + 8)  = *(const float4*)(wr + 8);
        *(float4*)(wv + 12) = *(const float4*)(wr + 12);
        float h0 = h_lds[rg * 2][k];
        float h1 = h_lds[rg * 2 + 1][k];
        #pragma unroll
        for (int j = 0; j < 16; ++j) {
            a0[j] = fmaf(h0, wv[j], a0[j]);
            a1[j] = fmaf(h1, wv[j], a1[j]);
        }
    }
    #pragma unroll
    for (int a = 0; a < 2; ++a) {
        long r = r0 + rg * 2 + a;
        if (r < NP) {
            long base = r * 256 + cg * 16;
            #pragma unroll
            for (int j = 0; j < 16; ++j)
                z[base + j] = f2b((a == 0 ? a0[j] : a1[j]) + p1_b[cg * 16 + j]);
        }
    }
}

// ---- BN1 stats from z (whoever wrote it)
__global__ void kstat(const unsigned short* __restrict__ z, float* __restrict__ part1) {
    int f = threadIdx.x;  // 256
    float s = 0.f, q = 0.f;
    for (long r = blockIdx.x; r < NP; r += gridDim.x) {
        float v = b2f(z[r * 256 + f]);
        s += v; q += v * v;
    }
    int bucket = blockIdx.x & 63;
    atomicAdd(&part1[bucket * 512 + f], s);
    atomicAdd(&part1[bucket * 512 + 256 + f], q);
}

// ---- finalize BN1
__global__ void k2(const float* __restrict__ part1, const float* __restrict__ g,
                   const float* __restrict__ beta, float* __restrict__ bn1) {
    int f = threadIdx.x;  // 256
    float s = 0.f, q = 0.f;
    for (int b = 0; b < 64; ++b) { s += part1[b * 512 + f]; q += part1[b * 512 + 256 + f]; }
    float mu = s / (float)NP;
    float var = fmaxf(q / (float)NP - mu * mu, 0.f);
    float a = rsqrtf(var + EPS) * g[f];
    bn1[f] = a;
    bn1[256 + f] = beta[f] - mu * a;
}

// ---- per molecule: segment mean of relu(BN(z)), then @ p3_W + p3_b
__global__ void k3(const unsigned short* __restrict__ z, const int* __restrict__ offs,
                   const float* __restrict__ bn1, const float* __restrict__ p3_W,
                   const float* __restrict__ p3_b, float* __restrict__ hpair) {
    int mol = blockIdx.x;
    int tid = threadIdx.x;  // 256
    int s = offs[mol], e = offs[mol + 1];
    float a = bn1[tid], c = bn1[256 + tid];
    float T = 0.f;
    for (int r = s; r < e; ++r)
        T += fmaxf(fmaf(b2f(z[(long)r * 256 + tid]), a, c), 0.f);
    __shared__ float Tl[256];
    Tl[tid] = T / (float)(e - s);
    __syncthreads();
    int f = tid & 127, half = tid >> 7;
    float acc = 0.f;
    const float* W = p3_W + half * 128 * 128 + f;
    #pragma unroll 4
    for (int kk = 0; kk < 128; ++kk) acc = fmaf(Tl[half * 128 + kk], W[kk * 128], acc);
    __shared__ float red[256];
    red[tid] = acc;
    __syncthreads();
    if (tid < 128) hpair[(long)mol * 128 + tid] = red[tid] + red[128 + tid] + p3_b[tid];
}

// ---- y1 = h_pair @ fc1_W + b, BN2 stats
__global__ void k4(const float* __restrict__ hpair, const float* __restrict__ fc1_W,
                   const float* __restrict__ fc1_b, float* __restrict__ y1,
                   float* __restrict__ part2) {
    __shared__ float hp[16][128];
    __shared__ float st2[256];
    int tid = threadIdx.x;
    int base = blockIdx.x * 16;
    st2[tid] = 0.f;
    for (int i = tid; i < 16 * 128; i += 256)
        hp[i >> 7][i & 127] = hpair[(long)(base + (i >> 7)) * 128 + (i & 127)];
    __syncthreads();
    int f = tid & 127, rh = tid >> 7;
    float s = 0.f, q = 0.f;
    float bias = fc1_b[f];
    for (int rr = 0; rr < 8; ++rr) {
        int row = rh * 8 + rr;
        float acc = bias;
        #pragma unroll 4
        for (int k = 0; k < 128; ++k) acc = fmaf(hp[row][k], fc1_W[k * 128 + f], acc);
        y1[(long)(base + row) * 128 + f] = acc;
        s += acc; q += acc * acc;
    }
    atomicAdd(&st2[f], s);
    atomicAdd(&st2[128 + f], q);
    __syncthreads();
    int bucket = blockIdx.x & 63;
    atomicAdd(&part2[bucket * 256 + tid], st2[tid]);
}

// ---- finalize BN2
__global__ void k5(const float* __restrict__ part2, const float* __restrict__ g,
                   const float* __restrict__ beta, float* __restrict__ bn2) {
    int f = threadIdx.x;  // 128
    float s = 0.f, q = 0.f;
    for (int b = 0; b < 64; ++b) { s += part2[b * 256 + f]; q += part2[b * 256 + 128 + f]; }
    float mu = s / (float)NM;
    float var = fmaxf(q / (float)NM - mu * mu, 0.f);
    float a = rsqrtf(var + EPS) * g[f];
    bn2[f] = a;
    bn2[128 + f] = beta[f] - mu * a;
}

// ---- out = relu(BN2(y1)) @ fc2_W + fc2_b
__global__ void k6(const float* __restrict__ y1, const float* __restrict__ bn2,
                   const float* __restrict__ fc2_W, const float* __restrict__ fc2_b,
                   float* __restrict__ out) {
    int mol = blockIdx.x * 256 + threadIdx.x;
    if (mol >= NM) return;
    float acc = fc2_b[0];
    const float4* yp = (const float4*)(y1 + (long)mol * 128);
    #pragma unroll 8
    for (int i = 0; i < 32; ++i) {
        float4 y = yp[i];
        float4 a = *(const float4*)(bn2 + i * 4);
        float4 c = *(const float4*)(bn2 + 128 + i * 4);
        float4 wv = *(const float4*)(fc2_W + i * 4);
        acc += fmaxf(fmaf(y.x, a.x, c.x), 0.f) * wv.x;
        acc += fmaxf(fmaf(y.y, a.y, c.y), 0.f) * wv.y;
        acc += fmaxf(fmaf(y.z, a.z, c.z), 0.f) * wv.z;
        acc += fmaxf(fmaf(y.w, a.w, c.w), 0.f) * wv.w;
    }
    out[mol] = acc;
}

extern "C" void kernel_launch(void* const* d_in, const int* in_sizes, int n_in,
                              void* d_out, int out_size, void* d_ws, size_t ws_size,
                              hipStream_t stream) {
    const float* xp     = (const float*)d_in[0];
    const int*   lens   = (const int*)d_in[1];
    const float* atom_W = (const float*)d_in[2];
    const float* atom_b = (const float*)d_in[3];
    const float* bond_W = (const float*)d_in[4];
    const float* bond_b = (const float*)d_in[5];
    const float* p1_W   = (const float*)d_in[6];
    const float* p1_b   = (const float*)d_in[7];
    const float* p_bn_g = (const float*)d_in[8];
    const float* p_bn_b = (const float*)d_in[9];
    const float* p3_W   = (const float*)d_in[10];
    const float* p3_b   = (const float*)d_in[11];
    const float* fc1_W  = (const float*)d_in[12];
    const float* fc1_b  = (const float*)d_in[13];
    const float* bn1_g  = (const float*)d_in[14];
    const float* bn1_b  = (const float*)d_in[15];
    const float* fc2_W  = (const float*)d_in[16];
    const float* fc2_b  = (const float*)d_in[17];
    float* out = (float*)d_out;
    char* ws = (char*)d_ws;

    int*   offs  = (int*)(ws + WS_OFFS);
    int*   flag  = (int*)(ws + WS_FLAG);
    float* part1 = (float*)(ws + WS_PART1);
    float* part2 = (float*)(ws + WS_PART2);
    float* bn1   = (float*)(ws + WS_BN1);
    float* bn2   = (float*)(ws + WS_BN2);
    unsigned short* wep = (unsigned short*)(ws + WS_WE);
    unsigned short* w1p = (unsigned short*)(ws + WS_W1);
    float* hpair = (float*)(ws + WS_HPAIR);
    float* y1    = (float*)(ws + WS_Y1);
    unsigned short* z = (unsigned short*)(ws + WS_Z);

    kprep<<<1, 256, 0, stream>>>(lens, offs, part1, part2, flag);
    kpack_we<<<120, 256, 0, stream>>>(atom_W, bond_W, wep);
    kpack_w1<<<320, 256, 0, stream>>>(p1_W, w1p);
    k1m<<<(NP + 63) / 64, 256, 0, stream>>>(xp, atom_b, bond_b, wep, w1p, p1_b, z);
    kverify<<<16, 256, 0, stream>>>(xp, atom_W, atom_b, bond_W, bond_b, p1_W, p1_b, z, flag);
    k1f<<<(NP + 31) / 32, 256, 0, stream>>>(flag, xp, atom_W, atom_b, bond_W, bond_b, p1_W, p1_b, z);
    kstat<<<2048, 256, 0, stream>>>(z, part1);
    k2<<<1, 256, 0, stream>>>(part1, p_bn_g, p_bn_b, bn1);
    k3<<<NM, 256, 0, stream>>>(z, offs, bn1, p3_W, p3_b, hpair);
    k4<<<(NM + 15) / 16, 256, 0, stream>>>(hpair, fc1_W, fc1_b, y1, part2);
    k5<<<1, 128, 0, stream>>>(part2, bn1_g, bn1_b, bn2);
    k6<<<(NM + 255) / 256, 256, 0, stream>>>(y1, bn2, fc2_W, fc2_b, out);
}